// Round 2
// baseline (388.133 us; speedup 1.0000x reference)
//
#include <hip/hip_runtime.h>
#include <hip/hip_bf16.h>

#define NN 50000
#define NE 800000
#define CH 64

typedef __attribute__((ext_vector_type(4))) float f4;

// ---- ws layout (in floats) ----
#define OFF_TX1 0                    // [NN*CH] scatter accumulator
#define OFF_DEG (NN*CH)              // [NN]    degree -> dinv (in place)
#define OFF_WT  (OFF_DEG + NN)       // [CH][4][CH] transposed f32 weights
#define OFF_BZ  (OFF_WT + 4*CH*CH)   // [CH] bx_z + bh_z
#define OFF_BH  (OFF_BZ + CH)        // [CH] bx_h + bh_h
#define OFF_LW  (OFF_BH + CH)        // [CH] lin_W
#define OFF_LB  (OFF_LW + CH)        // [1]  lin_b

// Transpose weights to [c][g][k] (g: 0=Wxz0 1=Wxz1 2=Wxh0 3=Wxh1), fold biases.
__global__ void k_prep(const float* __restrict__ Wxz, const float* __restrict__ bxz,
                       const float* __restrict__ bhz,
                       const float* __restrict__ Wxh, const float* __restrict__ bxh,
                       const float* __restrict__ bhh,
                       const float* __restrict__ linW, const float* __restrict__ linb,
                       float* __restrict__ ws) {
    int idx = blockIdx.x * 256 + threadIdx.x;
    if (idx < 4 * CH * CH) {
        int c = idx >> 8;      // output channel
        int r = idx & 255;
        int g = r >> 6;
        int k = r & 63;        // input channel
        float v;
        if      (g == 0) v = Wxz[k * CH + c];
        else if (g == 1) v = Wxz[CH * CH + k * CH + c];
        else if (g == 2) v = Wxh[k * CH + c];
        else             v = Wxh[CH * CH + k * CH + c];
        ws[OFF_WT + idx] = v;
    }
    if (idx < CH) {
        ws[OFF_BZ + idx] = bxz[idx] + bhz[idx];
        ws[OFF_BH + idx] = bxh[idx] + bhh[idx];
        ws[OFF_LW + idx] = linW[idx];
    }
    if (idx == 0) ws[OFF_LB] = linb[0];
}

__global__ void k_deg(const int* __restrict__ ei, const float* __restrict__ ew,
                      float* __restrict__ deg) {
    int e = blockIdx.x * 256 + threadIdx.x;
    if (e < NE) {
        unsafeAtomicAdd(&deg[ei[e]], ew[e]);
    }
}

__global__ void k_dinv(float* __restrict__ deg) {
    int i = blockIdx.x * 256 + threadIdx.x;
    if (i < NN) {
        float d = deg[i];
        deg[i] = (d > 0.f) ? (1.f / sqrtf(d)) : 0.f;
    }
}

// wave per edge, lane per channel: tx1[dst][c] += norm * x[src][c]
__global__ void k_scatter(const float* __restrict__ x, const int* __restrict__ ei,
                          const float* __restrict__ ew, const float* __restrict__ dinv,
                          float* __restrict__ tx1) {
    long long t = (long long)blockIdx.x * 256 + threadIdx.x;
    int e = (int)(t >> 6);
    int c = (int)(t & 63);
    if (e >= NE) return;
    int s = ei[e];
    int d = ei[NE + e];
    float nrm = -dinv[s] * ew[e] * dinv[d];
    float xv = x[(size_t)s * CH + c];
    unsafeAtomicAdd(&tx1[(size_t)d * CH + c], nrm * xv);
}

// thread per node: fused dual-gate 128->128 contraction + activations + head dot
__global__ __launch_bounds__(256) void k_node(const float* __restrict__ x,
                                              const float* __restrict__ ws,
                                              float* __restrict__ out) {
    int i = blockIdx.x * 256 + threadIdx.x;
    if (i >= NN) return;

    const float* __restrict__ WT = ws + OFF_WT;
    const float* __restrict__ BZ = ws + OFF_BZ;
    const float* __restrict__ BH = ws + OFF_BH;
    const float* __restrict__ LW = ws + OFF_LW;
    const float  LB = ws[OFF_LB];

    float xr[CH], tr[CH];
    {
        const f4* xp = (const f4*)(x + (size_t)i * CH);
        const f4* tp = (const f4*)(ws + OFF_TX1 + (size_t)i * CH);
#pragma unroll
        for (int j = 0; j < 16; j++) {
            f4 xv = xp[j];
            f4 tv = tp[j];
#pragma unroll
            for (int q = 0; q < 4; q++) {
                xr[j * 4 + q] = xv[q];
                tr[j * 4 + q] = tv[q];
            }
        }
    }

    float acc = 0.f;
    for (int c = 0; c < CH; c++) {
        const float* __restrict__ w = WT + c * 256;
        float s0 = 0.f, s1 = 0.f, s2 = 0.f, s3 = 0.f;
        float s4 = 0.f, s5 = 0.f, s6 = 0.f, s7 = 0.f;
#pragma unroll
        for (int k = 0; k < CH; k += 2) {
            s0 += xr[k]     * w[k];
            s1 += xr[k + 1] * w[k + 1];
            s2 += tr[k]     * w[64 + k];
            s3 += tr[k + 1] * w[64 + k + 1];
            s4 += xr[k]     * w[128 + k];
            s5 += xr[k + 1] * w[128 + k + 1];
            s6 += tr[k]     * w[192 + k];
            s7 += tr[k + 1] * w[192 + k + 1];
        }
        float az = BZ[c] + ((s0 + s1) + (s2 + s3));
        float ah = BH[c] + ((s4 + s5) + (s6 + s7));
        float z  = 1.f / (1.f + expf(-az));
        float ht = tanhf(ah);
        float h  = (1.f - z) * ht;
        h = (h > 0.f) ? h : 0.f;
        acc = fmaf(h, LW[c], acc);
    }
    out[i] = acc + LB;
}

extern "C" void kernel_launch(void* const* d_in, const int* in_sizes, int n_in,
                              void* d_out, int out_size, void* d_ws, size_t ws_size,
                              hipStream_t stream) {
    const float* x   = (const float*)d_in[0];
    const int*   ei  = (const int*)d_in[1];
    const float* ew  = (const float*)d_in[2];
    const float* Wxz = (const float*)d_in[3];
    const float* bxz = (const float*)d_in[4];
    const float* bhz = (const float*)d_in[6];
    const float* Wxh = (const float*)d_in[11];
    const float* bxh = (const float*)d_in[12];
    const float* bhh = (const float*)d_in[14];
    const float* lW  = (const float*)d_in[15];
    const float* lb  = (const float*)d_in[16];
    float* ws  = (float*)d_ws;
    float* out = (float*)d_out;

    // zero tx1 + deg accumulators (ws poisoned 0xAA once; must re-zero every call)
    hipMemsetAsync(ws, 0, (size_t)OFF_WT * sizeof(float), stream);

    k_prep<<<64, 256, 0, stream>>>(Wxz, bxz, bhz, Wxh, bxh, bhh, lW, lb, ws);
    k_deg<<<(NE + 255) / 256, 256, 0, stream>>>(ei, ew, ws + OFF_DEG);
    k_dinv<<<(NN + 255) / 256, 256, 0, stream>>>(ws + OFF_DEG);
    k_scatter<<<(NE * 64) / 256, 256, 0, stream>>>(x, ei, ew, ws + OFF_DEG, ws + OFF_TX1);
    k_node<<<(NN + 255) / 256, 256, 0, stream>>>(x, ws, out);
}